// Round 1
// baseline (1230.913 us; speedup 1.0000x reference)
//
#include <hip/hip_runtime.h>
#include <math.h>

// Problem constants (match reference)
#define BAGS 8
#define NINST 16384
#define DIM 768
#define NCLUST 8
#define NCLASS 2

constexpr int BLOCK = 256;                         // 4 waves
constexpr int WAVES_PER_BLOCK = BLOCK / 64;
constexpr int BLOCKS_PER_BAG = 256;
constexpr int ROWS_PER_BLOCK = NINST / BLOCKS_PER_BAG;           // 64
constexpr int ROWS_PER_WAVE = ROWS_PER_BLOCK / WAVES_PER_BLOCK;  // 16

// Each wave processes ROWS_PER_WAVE consecutive rows of one bag.
// Per row: 64 lanes x 3 float4 = 768 floats (coalesced), dot with both head
// rows, select-accumulate into lane-local acc[cluster][class] (label is
// wave-uniform). End: shuffle-reduce 16 accumulators, atomicAdd to d_ws.
__global__ __launch_bounds__(BLOCK) void reduce_kernel(
    const float* __restrict__ inst,      // [BAGS, NINST, DIM]
    const int* __restrict__ labels,      // [BAGS, NINST]
    const float* __restrict__ head_w,    // [NCLASS, DIM]
    float* __restrict__ sums,            // [BAGS*NCLUST, NCLASS]
    float* __restrict__ counts)          // [BAGS*NCLUST]
{
    const int bag  = blockIdx.y;
    const int wave = threadIdx.x >> 6;
    const int lane = threadIdx.x & 63;
    const int row0 = blockIdx.x * ROWS_PER_BLOCK + wave * ROWS_PER_WAVE;

    // Preload head_w fragments: lane l owns float4 slots {l, l+64, l+128}.
    const float4* w0p = (const float4*)(head_w);
    const float4* w1p = (const float4*)(head_w + DIM);
    float4 w0[3], w1[3];
#pragma unroll
    for (int i = 0; i < 3; ++i) {
        w0[i] = w0p[lane + i * 64];
        w1[i] = w1p[lane + i * 64];
    }

    float acc0[NCLUST], acc1[NCLUST];
    int cnt[NCLUST];
#pragma unroll
    for (int c = 0; c < NCLUST; ++c) { acc0[c] = 0.f; acc1[c] = 0.f; cnt[c] = 0; }

    const int*    lab_base = labels + (size_t)bag * NINST;
    const float4* x_base   = (const float4*)(inst + (size_t)bag * NINST * DIM);

    for (int r = 0; r < ROWS_PER_WAVE; ++r) {
        const int row = row0 + r;
        const int lab = lab_base[row];                 // wave-uniform
        const float4* xp = x_base + (size_t)row * (DIM / 4);

        float d0 = 0.f, d1 = 0.f;
#pragma unroll
        for (int i = 0; i < 3; ++i) {
            float4 x = xp[lane + i * 64];
            d0 = fmaf(x.x, w0[i].x, d0); d0 = fmaf(x.y, w0[i].y, d0);
            d0 = fmaf(x.z, w0[i].z, d0); d0 = fmaf(x.w, w0[i].w, d0);
            d1 = fmaf(x.x, w1[i].x, d1); d1 = fmaf(x.y, w1[i].y, d1);
            d1 = fmaf(x.z, w1[i].z, d1); d1 = fmaf(x.w, w1[i].w, d1);
        }
#pragma unroll
        for (int c = 0; c < NCLUST; ++c) {
            const bool m = (lab == c);
            acc0[c] += m ? d0 : 0.f;
            acc1[c] += m ? d1 : 0.f;
            cnt[c]  += m ? 1 : 0;
        }
    }

    // Wave reduction of the 16 accumulators; counts are identical on all
    // lanes (every lane saw the same rows), so lane 0's value is exact.
#pragma unroll
    for (int c = 0; c < NCLUST; ++c) {
        float a0 = acc0[c], a1 = acc1[c];
#pragma unroll
        for (int off = 32; off >= 1; off >>= 1) {
            a0 += __shfl_down(a0, off, 64);
            a1 += __shfl_down(a1, off, 64);
        }
        if (lane == 0) {
            const int seg = bag * NCLUST + c;
            atomicAdd(&sums[seg * NCLASS + 0], a0);
            atomicAdd(&sums[seg * NCLASS + 1], a1);
            atomicAdd(&counts[seg], (float)cnt[c]);
        }
    }
}

// One block, 64 threads: thread t -> (bag = t/8, cluster = t%8).
// mean-logits, softmax, score = 1 - p[NOR_INDEX=0], argmax over clusters
// (ties -> lowest cluster index, matching jnp.argmax), write winner logits.
__global__ __launch_bounds__(64) void finalize_kernel(
    const float* __restrict__ sums,
    const float* __restrict__ counts,
    const float* __restrict__ head_b,
    float* __restrict__ out)             // [BAGS, NCLASS]
{
    const int t   = threadIdx.x;
    const int bag = t >> 3;
    const int c   = t & 7;
    const int seg = bag * NCLUST + c;

    const float denom = fmaxf(counts[seg], 1.f);
    const float l0 = sums[seg * NCLASS + 0] / denom + head_b[0];
    const float l1 = sums[seg * NCLASS + 1] / denom + head_b[1];

    const float m  = fmaxf(l0, l1);
    const float e0 = expf(l0 - m);
    const float e1 = expf(l1 - m);
    const float score = 1.f - e0 / (e0 + e1);

    float bs = score; int bc = c; float bl0 = l0, bl1 = l1;
#pragma unroll
    for (int off = 1; off < 8; off <<= 1) {   // xor masks 1,2,4 stay in 8-lane group
        const float os  = __shfl_xor(bs, off, 64);
        const int   oc  = __shfl_xor(bc, off, 64);
        const float ol0 = __shfl_xor(bl0, off, 64);
        const float ol1 = __shfl_xor(bl1, off, 64);
        if (os > bs || (os == bs && oc < bc)) { bs = os; bc = oc; bl0 = ol0; bl1 = ol1; }
    }
    if (c == 0) {
        out[bag * NCLASS + 0] = bl0;
        out[bag * NCLASS + 1] = bl1;
    }
}

extern "C" void kernel_launch(void* const* d_in, const int* in_sizes, int n_in,
                              void* d_out, int out_size, void* d_ws, size_t ws_size,
                              hipStream_t stream) {
    const float* inst   = (const float*)d_in[0];   // [B,N,D] fp32
    const int*   labels = (const int*)d_in[1];     // [B,N] int32
    const float* head_w = (const float*)d_in[2];   // [NC,D] fp32
    const float* head_b = (const float*)d_in[3];   // [NC] fp32
    float* out = (float*)d_out;                    // [B,NC] fp32

    float* sums   = (float*)d_ws;                         // 128 floats
    float* counts = sums + BAGS * NCLUST * NCLASS;        // 64 floats

    // ws is re-poisoned to 0xAA before every call — zero our accumulators.
    hipMemsetAsync(d_ws, 0, (size_t)(BAGS * NCLUST * NCLASS + BAGS * NCLUST) * sizeof(float), stream);

    dim3 grid(BLOCKS_PER_BAG, BAGS);
    reduce_kernel<<<grid, BLOCK, 0, stream>>>(inst, labels, head_w, sums, counts);
    finalize_kernel<<<1, 64, 0, stream>>>(sums, counts, head_b, out);
}

// Round 2
// 530.411 us; speedup vs baseline: 2.3207x; 2.3207x over previous
//
#include <hip/hip_runtime.h>
#include <math.h>

// Problem constants (match reference)
#define BAGS 8
#define NINST 16384
#define DIM 768
#define NCLUST 8
#define NCLASS 2

constexpr int BLOCK = 256;                         // 4 waves
constexpr int WAVES_PER_BLOCK = BLOCK / 64;
constexpr int BLOCKS_PER_BAG = 256;
constexpr int NBLOCKS = BLOCKS_PER_BAG * BAGS;                   // 2048
constexpr int ROWS_PER_BLOCK = NINST / BLOCKS_PER_BAG;           // 64
constexpr int ROWS_PER_WAVE = ROWS_PER_BLOCK / WAVES_PER_BLOCK;  // 16
constexpr int NCOMP = NCLUST * NCLASS + NCLUST;                  // 16 sums + 8 counts = 24

// ws layout (component-major so stage-2 reads are contiguous):
//   ws[comp * NBLOCKS + blockLinear],  comp<16: (c<<1)|cls sums, comp 16..23: counts[c]
//
// Stage 1: each wave streams 16 rows (64 lanes x 3 float4 = row), dots with
// both head rows, select-accumulates into lane-local acc[cluster][class]
// (label is wave-uniform). Rows processed 4 at a time so 12 independent
// dwordx4 loads are in flight per wave. End: shuffle-reduce, LDS-combine
// across the 4 waves, plain stores of 24 block partials. NO atomics — R1
// showed 196K same-line memory-side atomics cost ~700 us (WRITE_SIZE 6 MB).
__global__ __launch_bounds__(BLOCK) void reduce_kernel(
    const float* __restrict__ inst,      // [BAGS, NINST, DIM]
    const int* __restrict__ labels,      // [BAGS, NINST]
    const float* __restrict__ head_w,    // [NCLASS, DIM]
    float* __restrict__ ws)              // [NCOMP, NBLOCKS]
{
    const int bag  = blockIdx.y;
    const int wave = threadIdx.x >> 6;
    const int lane = threadIdx.x & 63;
    const int row0 = blockIdx.x * ROWS_PER_BLOCK + wave * ROWS_PER_WAVE;

    // Preload head_w fragments: lane l owns float4 slots {l, l+64, l+128}.
    const float4* w0p = (const float4*)(head_w);
    const float4* w1p = (const float4*)(head_w + DIM);
    float4 w0[3], w1[3];
#pragma unroll
    for (int i = 0; i < 3; ++i) {
        w0[i] = w0p[lane + i * 64];
        w1[i] = w1p[lane + i * 64];
    }

    float acc0[NCLUST], acc1[NCLUST];
    int cnt[NCLUST];
#pragma unroll
    for (int c = 0; c < NCLUST; ++c) { acc0[c] = 0.f; acc1[c] = 0.f; cnt[c] = 0; }

    const int*    lab_base = labels + (size_t)bag * NINST;
    const float4* x_base   = (const float4*)(inst + (size_t)bag * NINST * DIM);

    for (int rr = 0; rr < ROWS_PER_WAVE; rr += 4) {
        float4 x[4][3];
        int lab[4];
#pragma unroll
        for (int r = 0; r < 4; ++r) {
            const int row = row0 + rr + r;
            lab[r] = lab_base[row];
            const float4* xp = x_base + (size_t)row * (DIM / 4);
#pragma unroll
            for (int i = 0; i < 3; ++i) x[r][i] = xp[lane + i * 64];
        }
#pragma unroll
        for (int r = 0; r < 4; ++r) {
            float d0 = 0.f, d1 = 0.f;
#pragma unroll
            for (int i = 0; i < 3; ++i) {
                d0 = fmaf(x[r][i].x, w0[i].x, d0); d0 = fmaf(x[r][i].y, w0[i].y, d0);
                d0 = fmaf(x[r][i].z, w0[i].z, d0); d0 = fmaf(x[r][i].w, w0[i].w, d0);
                d1 = fmaf(x[r][i].x, w1[i].x, d1); d1 = fmaf(x[r][i].y, w1[i].y, d1);
                d1 = fmaf(x[r][i].z, w1[i].z, d1); d1 = fmaf(x[r][i].w, w1[i].w, d1);
            }
#pragma unroll
            for (int c = 0; c < NCLUST; ++c) {
                const bool m = (lab[r] == c);
                acc0[c] += m ? d0 : 0.f;
                acc1[c] += m ? d1 : 0.f;
                cnt[c]  += m ? 1 : 0;
            }
        }
    }

    // Wave reduction of the 16 sum accumulators; counts are wave-uniform
    // (every lane saw the same rows), so lane 0's value is exact.
    __shared__ float lds_s[WAVES_PER_BLOCK][NCLUST * NCLASS];
    __shared__ float lds_c[WAVES_PER_BLOCK][NCLUST];
#pragma unroll
    for (int c = 0; c < NCLUST; ++c) {
        float a0 = acc0[c], a1 = acc1[c];
#pragma unroll
        for (int off = 32; off >= 1; off >>= 1) {
            a0 += __shfl_down(a0, off, 64);
            a1 += __shfl_down(a1, off, 64);
        }
        if (lane == 0) {
            lds_s[wave][c * 2 + 0] = a0;
            lds_s[wave][c * 2 + 1] = a1;
            lds_c[wave][c] = (float)cnt[c];
        }
    }
    __syncthreads();

    const int bid = blockIdx.y * gridDim.x + blockIdx.x;   // bag*256 + x
    const int t = threadIdx.x;
    if (t < NCLUST * NCLASS) {
        const float s = lds_s[0][t] + lds_s[1][t] + lds_s[2][t] + lds_s[3][t];
        ws[t * NBLOCKS + bid] = s;
    } else if (t < NCOMP) {
        const int c = t - NCLUST * NCLASS;
        const float s = lds_c[0][c] + lds_c[1][c] + lds_c[2][c] + lds_c[3][c];
        ws[t * NBLOCKS + bid] = s;
    }
}

// One block: threads 0..191 each sum the 256 contiguous partials of one
// (bag, comp) accumulator (float4 loads, all L2-resident), then threads
// 0..63 do mean-logits, softmax, score = 1 - p[NOR_INDEX=0], argmax over
// clusters (ties -> lowest index, matching jnp.argmax), write winner logits.
__global__ __launch_bounds__(256) void finalize_kernel(
    const float* __restrict__ ws,
    const float* __restrict__ head_b,
    float* __restrict__ out)             // [BAGS, NCLASS]
{
    __shared__ float red[BAGS][NCOMP];
    const int t = threadIdx.x;

    if (t < BAGS * NCOMP) {
        const int bag = t / NCOMP;
        const int comp = t % NCOMP;
        const float4* p = (const float4*)(ws + (size_t)comp * NBLOCKS + bag * BLOCKS_PER_BAG);
        float4 a = make_float4(0.f, 0.f, 0.f, 0.f);
#pragma unroll 4
        for (int i = 0; i < BLOCKS_PER_BAG / 4; ++i) {
            float4 v = p[i];
            a.x += v.x; a.y += v.y; a.z += v.z; a.w += v.w;
        }
        red[bag][comp] = (a.x + a.y) + (a.z + a.w);
    }
    __syncthreads();

    if (t < BAGS * NCLUST) {
        const int bag = t >> 3;
        const int c   = t & 7;

        const float denom = fmaxf(red[bag][NCLUST * NCLASS + c], 1.f);
        const float l0 = red[bag][c * 2 + 0] / denom + head_b[0];
        const float l1 = red[bag][c * 2 + 1] / denom + head_b[1];

        const float m  = fmaxf(l0, l1);
        const float e0 = expf(l0 - m);
        const float e1 = expf(l1 - m);
        const float score = 1.f - e0 / (e0 + e1);

        float bs = score; int bc = c; float bl0 = l0, bl1 = l1;
#pragma unroll
        for (int off = 1; off < 8; off <<= 1) {  // xor 1,2,4 stay within the 8-lane group
            const float os  = __shfl_xor(bs, off, 64);
            const int   oc  = __shfl_xor(bc, off, 64);
            const float ol0 = __shfl_xor(bl0, off, 64);
            const float ol1 = __shfl_xor(bl1, off, 64);
            if (os > bs || (os == bs && oc < bc)) { bs = os; bc = oc; bl0 = ol0; bl1 = ol1; }
        }
        if (c == 0) {
            out[bag * NCLASS + 0] = bl0;
            out[bag * NCLASS + 1] = bl1;
        }
    }
}

extern "C" void kernel_launch(void* const* d_in, const int* in_sizes, int n_in,
                              void* d_out, int out_size, void* d_ws, size_t ws_size,
                              hipStream_t stream) {
    const float* inst   = (const float*)d_in[0];   // [B,N,D] fp32
    const int*   labels = (const int*)d_in[1];     // [B,N] int32
    const float* head_w = (const float*)d_in[2];   // [NC,D] fp32
    const float* head_b = (const float*)d_in[3];   // [NC] fp32
    float* out = (float*)d_out;                    // [B,NC] fp32

    float* ws = (float*)d_ws;   // NCOMP * NBLOCKS floats = 192 KiB, fully
                                // written by stage 1 before stage 2 reads it
                                // -> no zero-init needed (0xAA poison is fine).

    dim3 grid(BLOCKS_PER_BAG, BAGS);
    reduce_kernel<<<grid, BLOCK, 0, stream>>>(inst, labels, head_w, ws);
    finalize_kernel<<<1, 256, 0, stream>>>(ws, head_b, out);
}